// Round 1
// baseline (789.541 us; speedup 1.0000x reference)
//
#include <hip/hip_runtime.h>

typedef __attribute__((ext_vector_type(8))) short short8v;
typedef __attribute__((ext_vector_type(4))) short short4v;
typedef __attribute__((ext_vector_type(4))) float floatx4;

#define S_    2048
#define DIM_  2048
#define NH_   16
#define HD_   128

__device__ __forceinline__ short f2bf(float f){
  union { float f; unsigned u; } c; c.f = f;
  unsigned u = c.u;
  unsigned r = (u + 0x7fffu + ((u >> 16) & 1u)) >> 16;
  return (short)r;
}
__device__ __forceinline__ float bf2f(short s){
  union { unsigned u; float f; } c; c.u = ((unsigned)(unsigned short)s) << 16;
  return c.f;
}

// ---------------- f32 -> bf16 convert ----------------
__global__ __launch_bounds__(256) void cvt_k(const float* __restrict__ in,
                                             short* __restrict__ out, int n){
  int i = blockIdx.x*256 + threadIdx.x;
  int idx = i*4;
  if (idx >= n) return;
  floatx4 v = *(const floatx4*)(in + idx);
  short4v o;
  o[0]=f2bf(v[0]); o[1]=f2bf(v[1]); o[2]=f2bf(v[2]); o[3]=f2bf(v[3]);
  *(short4v*)(out + idx) = o;
}

// ---------------- NT GEMM: C[m,n] = sum_k A[m,k]*B[n,k] (bf16 in, f32 acc) ---
// 128x128 tile, BK=64, 4 waves (2x2 of 64x64), 4x4 16x16 MFMA tiles per wave.
template<bool OUT_BF16>
__global__ __launch_bounds__(256,2)
void gemm_nt(const short* __restrict__ A, const short* __restrict__ B,
             void* __restrict__ Cout, int M, int N, int K){
  __shared__ short As[128][72];   // +8 pad: row stride 144B (16B-aligned)
  __shared__ short Bs[128][72];
  int tid = threadIdx.x;
  int wave = tid>>6, lane = tid&63, quad = lane>>4, l16 = lane&15;
  int m0 = blockIdx.x*128, n0 = blockIdx.y*128;
  int wm = (wave>>1)*64, wn = (wave&1)*64;
  floatx4 acc[4][4] = {};

  for (int k0 = 0; k0 < K; k0 += 64){
    __syncthreads();
    #pragma unroll
    for (int i=0;i<4;i++){
      int c = tid + 256*i;
      int r = c>>3, cc = (c&7)*8;
      *(short8v*)&As[r][cc] = *(const short8v*)&A[(size_t)(m0+r)*K + k0 + cc];
      int bn = n0 + r;
      short8v bv;
      #pragma unroll
      for (int u=0;u<8;u++) bv[u]=0;
      if (bn < N) bv = *(const short8v*)&B[(size_t)bn*K + k0 + cc];
      *(short8v*)&Bs[r][cc] = bv;
    }
    __syncthreads();
    #pragma unroll
    for (int ks=0; ks<2; ks++){
      short8v af[4], bf[4];
      #pragma unroll
      for (int i=0;i<4;i++) af[i] = *(short8v*)&As[wm + i*16 + l16][ks*32 + quad*8];
      #pragma unroll
      for (int j=0;j<4;j++) bf[j] = *(short8v*)&Bs[wn + j*16 + l16][ks*32 + quad*8];
      #pragma unroll
      for (int i=0;i<4;i++)
        #pragma unroll
        for (int j=0;j<4;j++)
          acc[i][j] = __builtin_amdgcn_mfma_f32_16x16x32_bf16(af[i], bf[j], acc[i][j], 0,0,0);
    }
  }
  // epilogue: C row = quad*4+reg, col = lane&15 (verified C/D layout)
  #pragma unroll
  for (int i=0;i<4;i++){
    #pragma unroll
    for (int r=0;r<4;r++){
      int gm = m0 + wm + i*16 + quad*4 + r;
      #pragma unroll
      for (int j=0;j<4;j++){
        int gn = n0 + wn + j*16 + l16;
        if (gn < N){
          if (OUT_BF16) ((short*)Cout)[(size_t)gm*N + gn] = f2bf(acc[i][j][r]);
          else          ((float*)Cout)[(size_t)gm*N + gn] = acc[i][j][r];
        }
      }
    }
  }
}

// ---------------- RoPE on Q and K in place (bf16) ----------------
__global__ __launch_bounds__(256) void rope_k(short* __restrict__ Q, short* __restrict__ Kv,
                                              const float* __restrict__ fcos,
                                              const float* __restrict__ fsin){
  int i = blockIdx.x*256 + threadIdx.x;   // pair index, 4096*1024 total
  int row = i >> 10;                      // b*S + s
  int p = i & 1023;                       // pair within row (h*64 + pp)
  int s = row & (S_-1);
  int pp = p & 63;
  float c = fcos[s*64+pp], sn = fsin[s*64+pp];
  size_t a = (size_t)row*DIM_ + p*2;
  {
    int v = *(int*)(Q + a);
    float re = bf2f((short)(v & 0xffff)), im = bf2f((short)(v >> 16));
    float orr = re*c - im*sn, oi = re*sn + im*c;
    *(int*)(Q + a) = ((int)(unsigned short)f2bf(oi) << 16) | (unsigned short)f2bf(orr);
  }
  {
    int v = *(int*)(Kv + a);
    float re = bf2f((short)(v & 0xffff)), im = bf2f((short)(v >> 16));
    float orr = re*c - im*sn, oi = re*sn + im*c;
    *(int*)(Kv + a) = ((int)(unsigned short)f2bf(oi) << 16) | (unsigned short)f2bf(orr);
  }
}

// ---------------- V transpose: Vt[b*2048 + n][s] = V[b*2048 + s][n] ---------
__global__ __launch_bounds__(256) void transpose_k(const short* __restrict__ V,
                                                   short* __restrict__ Vt){
  __shared__ short t[64][72];
  int b = blockIdx.z;
  int s0 = blockIdx.x*64, n0 = blockIdx.y*64;
  int tid = threadIdx.x;
  #pragma unroll
  for (int i=0;i<2;i++){
    int c = tid + 256*i;
    int r = c>>3, cc = (c&7)*8;
    *(short8v*)&t[r][cc] = *(const short8v*)&V[((size_t)(b*2048 + s0 + r))*2048 + n0 + cc];
  }
  __syncthreads();
  #pragma unroll
  for (int i=0;i<2;i++){
    int c = tid + 256*i;
    int r = c>>3, cc = (c&7)*8;
    short8v v;
    #pragma unroll
    for (int u=0;u<8;u++) v[u] = t[cc+u][r];
    *(short8v*)&Vt[((size_t)(b*2048 + n0 + r))*2048 + s0 + cc] = v;
  }
}

// ---------------- Flash attention with low-rank sigmoid gate ----------------
// Q,K: (B*S, 2048) bf16 (rope'd). Vt: (B*2048 rows=h*128+d, S) bf16.
// QKH: (B*S, 64) bf16, cols 0..31 = xq_h, 32..63 = xk_h. O: (B*S, 2048) bf16.
__global__ __launch_bounds__(256,2)
void flash_k(const short* __restrict__ Q, const short* __restrict__ Kk,
             const short* __restrict__ Vt, const short* __restrict__ QKH,
             short* __restrict__ O){
  const float scale = 0.08838834764831845f;  // 1/sqrt(128)
  int qt = blockIdx.x, h = blockIdx.y, b = blockIdx.z;
  int q0 = qt*64;
  int tid = threadIdx.x, wave = tid>>6, lane = tid&63, quad = lane>>4, l16 = lane&15;

  __shared__ short Ks [64][136];   // k-rows x d  (272B rows, 16B aligned)
  __shared__ short Vts[128][72];   // d-rows x k
  __shared__ short KHs[64][40];    // k-rows x rank
  __shared__ short Ps [4][16][72]; // per-wave P tile (q x k)

  size_t qrow = (size_t)(b*2048 + q0 + wave*16 + l16);
  short8v qf[4];
  #pragma unroll
  for (int ks=0;ks<4;ks++)
    qf[ks] = *(const short8v*)&Q[qrow*2048 + h*128 + ks*32 + quad*8];
  short8v qhf = *(const short8v*)&QKH[qrow*64 + quad*8];

  floatx4 oacc[8] = {};
  float mrow[4], lrow[4];
  #pragma unroll
  for (int r=0;r<4;r++){ mrow[r] = -1e30f; lrow[r] = 0.f; }

  int qmaxw = q0 + wave*16 + 15;

  for (int kt=0; kt<=qt; kt++){
    int k0 = kt*64;
    __syncthreads();
    #pragma unroll
    for (int i=0;i<4;i++){
      int c = tid + 256*i; int r = c>>4, cc = (c&15)*8;
      *(short8v*)&Ks[r][cc] = *(const short8v*)&Kk[((size_t)(b*2048 + k0 + r))*2048 + h*128 + cc];
    }
    #pragma unroll
    for (int i=0;i<4;i++){
      int c = tid + 256*i; int r = c>>3, cc = (c&7)*8;
      *(short8v*)&Vts[r][cc] = *(const short8v*)&Vt[((size_t)(b*2048 + h*128 + r))*2048 + k0 + cc];
    }
    { int r = tid>>2, cc = (tid&3)*8;
      *(short8v*)&KHs[r][cc] = *(const short8v*)&QKH[((size_t)(b*2048 + k0 + r))*64 + 32 + cc];
    }
    __syncthreads();

    bool active = (k0 <= qmaxw);
    if (active){
      floatx4 sacc[4] = {};
      floatx4 amacc[4] = {};
      #pragma unroll
      for (int j=0;j<4;j++){
        #pragma unroll
        for (int ks=0;ks<4;ks++){
          short8v bfr = *(short8v*)&Ks[j*16 + l16][ks*32 + quad*8];
          sacc[j] = __builtin_amdgcn_mfma_f32_16x16x32_bf16(qf[ks], bfr, sacc[j], 0,0,0);
        }
        short8v khf = *(short8v*)&KHs[j*16 + l16][quad*8];
        amacc[j] = __builtin_amdgcn_mfma_f32_16x16x32_bf16(qhf, khf, amacc[j], 0,0,0);
      }
      int qbase_l = q0 + wave*16 + quad*4;
      #pragma unroll
      for (int j=0;j<4;j++){
        int kcol = k0 + j*16 + l16;
        #pragma unroll
        for (int r=0;r<4;r++){
          float sv = sacc[j][r]*scale;
          sacc[j][r] = (kcol <= qbase_l + r) ? sv : -1e30f;
        }
      }
      #pragma unroll
      for (int r=0;r<4;r++){
        float t0 = fmaxf(fmaxf(sacc[0][r],sacc[1][r]), fmaxf(sacc[2][r],sacc[3][r]));
        #pragma unroll
        for (int off=1; off<16; off<<=1) t0 = fmaxf(t0, __shfl_xor(t0, off, 64));
        float mn = fmaxf(mrow[r], t0);
        float alpha = __expf(mrow[r] - mn);
        mrow[r] = mn;
        lrow[r] *= alpha;
        #pragma unroll
        for (int dt=0;dt<8;dt++) oacc[dt][r] *= alpha;
        float rsum = 0.f;
        #pragma unroll
        for (int j=0;j<4;j++){
          float p = __expf(sacc[j][r] - mn);
          rsum += p;
          float sg = 1.f/(1.f + __expf(-amacc[j][r]));
          Ps[wave][quad*4+r][j*16+l16] = f2bf(p*sg);
        }
        #pragma unroll
        for (int off=1; off<16; off<<=1) rsum += __shfl_xor(rsum, off, 64);
        lrow[r] += rsum;
      }
    }
    __syncthreads();
    if (active){
      #pragma unroll
      for (int ks=0; ks<2; ks++){
        short8v pf = *(short8v*)&Ps[wave][l16][ks*32 + quad*8];
        #pragma unroll
        for (int dt=0; dt<8; dt++){
          short8v vf = *(short8v*)&Vts[dt*16 + l16][ks*32 + quad*8];
          oacc[dt] = __builtin_amdgcn_mfma_f32_16x16x32_bf16(pf, vf, oacc[dt], 0,0,0);
        }
      }
    }
  }
  #pragma unroll
  for (int r=0;r<4;r++){
    float inv = 1.f/lrow[r];
    size_t orow = (size_t)(b*2048 + q0 + wave*16 + quad*4 + r);
    #pragma unroll
    for (int dt=0;dt<8;dt++)
      O[orow*2048 + h*128 + dt*16 + l16] = f2bf(oacc[dt][r]*inv);
  }
}

// ---------------- launch ----------------
extern "C" void kernel_launch(void* const* d_in, const int* in_sizes, int n_in,
                              void* d_out, int out_size, void* d_ws, size_t ws_size,
                              hipStream_t stream){
  const float* x    = (const float*)d_in[0];
  // d_in[1] = mask (causality is computed analytically; -1e9 ≡ exp()->0)
  const float* fcos = (const float*)d_in[2];
  const float* fsin = (const float*)d_in[3];
  const float* wq   = (const float*)d_in[4];
  const float* wk   = (const float*)d_in[5];
  const float* wv   = (const float*)d_in[6];
  const float* wo   = (const float*)d_in[7];
  const float* waq  = (const float*)d_in[8];
  const float* wak  = (const float*)d_in[9];
  float* out = (float*)d_out;

  char* ws = (char*)d_ws;
  size_t off = 0;
  const size_t SZ_ACT = (size_t)4096*2048*2;  // 16 MB bf16 activation
  const size_t SZ_W   = (size_t)2048*2048*2;  // 8 MB bf16 weight
  short* xb   = (short*)(ws + off); off += SZ_ACT;   // reused as O after GEMMs
  short* wqb  = (short*)(ws + off); off += SZ_W;
  short* wkb  = (short*)(ws + off); off += SZ_W;
  short* wvb  = (short*)(ws + off); off += SZ_W;
  short* wob  = (short*)(ws + off); off += SZ_W;
  short* wab  = (short*)(ws + off); off += (size_t)64*2048*2;
  short* Qb   = (short*)(ws + off); off += SZ_ACT;
  short* Kb   = (short*)(ws + off); off += SZ_ACT;
  short* Vb   = (short*)(ws + off); off += SZ_ACT;
  short* Vtb  = (short*)(ws + off); off += SZ_ACT;
  short* xqkh = (short*)(ws + off); off += (size_t)4096*64*2;
  short* Ob   = xb;  // x no longer needed after the four projection GEMMs

  // bf16 conversions
  cvt_k<<<8192,256,0,stream>>>(x,   xb,  8388608);
  cvt_k<<<4096,256,0,stream>>>(wq,  wqb, 4194304);
  cvt_k<<<4096,256,0,stream>>>(wk,  wkb, 4194304);
  cvt_k<<<4096,256,0,stream>>>(wv,  wvb, 4194304);
  cvt_k<<<4096,256,0,stream>>>(wo,  wob, 4194304);
  cvt_k<<<64,  256,0,stream>>>(waq, wab,         65536);
  cvt_k<<<64,  256,0,stream>>>(wak, wab + 65536, 65536);

  dim3 gBig(32,16);
  gemm_nt<true><<<gBig,256,0,stream>>>(xb, wqb, Qb, 4096, 2048, 2048);
  gemm_nt<true><<<gBig,256,0,stream>>>(xb, wkb, Kb, 4096, 2048, 2048);
  gemm_nt<true><<<gBig,256,0,stream>>>(xb, wvb, Vb, 4096, 2048, 2048);
  gemm_nt<true><<<dim3(32,1),256,0,stream>>>(xb, wab, xqkh, 4096, 64, 2048);

  rope_k<<<16384,256,0,stream>>>(Qb, Kb, fcos, fsin);
  transpose_k<<<dim3(32,32,2),256,0,stream>>>(Vb, Vtb);

  flash_k<<<dim3(32,16,2),256,0,stream>>>(Qb, Kb, Vtb, xqkh, Ob);

  gemm_nt<false><<<gBig,256,0,stream>>>(Ob, wob, out, 4096, 2048, 2048);
}

// Round 2
// 620.277 us; speedup vs baseline: 1.2729x; 1.2729x over previous
//
#include <hip/hip_runtime.h>

typedef __attribute__((ext_vector_type(8))) short short8v;
typedef __attribute__((ext_vector_type(4))) short short4v;
typedef __attribute__((ext_vector_type(4))) float floatx4;

#define S_    2048
#define DIM_  2048

#define ASG(p) ((__attribute__((address_space(1))) void*)(p))
#define ASL(p) ((__attribute__((address_space(3))) void*)(p))

__device__ __forceinline__ short f2bf(float f){
  union { float f; unsigned u; } c; c.f = f;
  unsigned u = c.u;
  unsigned r = (u + 0x7fffu + ((u >> 16) & 1u)) >> 16;
  return (short)r;
}
__device__ __forceinline__ float bf2f(short s){
  union { unsigned u; float f; } c; c.u = ((unsigned)(unsigned short)s) << 16;
  return c.f;
}

// ---------------- f32 -> bf16 convert ----------------
__global__ __launch_bounds__(256) void cvt_k(const float* __restrict__ in,
                                             short* __restrict__ out, int n){
  int i = blockIdx.x*256 + threadIdx.x;
  int idx = i*4;
  if (idx >= n) return;
  floatx4 v = *(const floatx4*)(in + idx);
  short4v o;
  o[0]=f2bf(v[0]); o[1]=f2bf(v[1]); o[2]=f2bf(v[2]); o[3]=f2bf(v[3]);
  *(short4v*)(out + idx) = o;
}

// ------------- fast NT GEMM (m97 pattern): M,N multiples of 128 -------------
template<bool OUT_BF16>
__global__ __launch_bounds__(256,2)
void gemm_nt_fast(const short* __restrict__ A, const short* __restrict__ B,
                  void* __restrict__ Cout, int M, int N, int K){
  __shared__ short As[128][64];
  __shared__ short Bs[128][64];
  int tid = threadIdx.x;
  int wave = tid>>6, lane = tid&63, quad = lane>>4, l16 = lane&15;
  int m0 = blockIdx.x*128, n0 = blockIdx.y*128;
  int wm = (wave>>1)*64, wn = (wave&1)*64;
  floatx4 acc[4][4] = {};

  int lr = lane>>3, lc = (lane&7)*8;
  const short* Abase = A + (size_t)(m0 + wave*32 + lr)*K + lc;
  const short* Bbase = B + (size_t)(n0 + wave*32 + lr)*K + lc;

  for (int k0 = 0; k0 < K; k0 += 64){
    __syncthreads();
    #pragma unroll
    for (int i=0;i<4;i++){
      __builtin_amdgcn_global_load_lds(ASG(Abase + (size_t)(i*8)*K + k0),
                                       ASL(&As[wave*32 + i*8][0]), 16, 0, 0);
      __builtin_amdgcn_global_load_lds(ASG(Bbase + (size_t)(i*8)*K + k0),
                                       ASL(&Bs[wave*32 + i*8][0]), 16, 0, 0);
    }
    __syncthreads();
    #pragma unroll
    for (int ks=0; ks<2; ks++){
      short8v af[4], bf[4];
      #pragma unroll
      for (int i=0;i<4;i++) af[i] = *(short8v*)&As[wm + i*16 + l16][ks*32 + quad*8];
      #pragma unroll
      for (int j=0;j<4;j++) bf[j] = *(short8v*)&Bs[wn + j*16 + l16][ks*32 + quad*8];
      #pragma unroll
      for (int i=0;i<4;i++)
        #pragma unroll
        for (int j=0;j<4;j++)
          acc[i][j] = __builtin_amdgcn_mfma_f32_16x16x32_bf16(af[i], bf[j], acc[i][j], 0,0,0);
    }
  }
  #pragma unroll
  for (int i=0;i<4;i++){
    #pragma unroll
    for (int r=0;r<4;r++){
      int gm = m0 + wm + i*16 + quad*4 + r;
      #pragma unroll
      for (int j=0;j<4;j++){
        int gn = n0 + wn + j*16 + l16;
        if (OUT_BF16) ((short*)Cout)[(size_t)gm*N + gn] = f2bf(acc[i][j][r]);
        else          ((float*)Cout)[(size_t)gm*N + gn] = acc[i][j][r];
      }
    }
  }
}

// ------------- guarded NT GEMM (register staging) for N=64 gate GEMM --------
__global__ __launch_bounds__(256,2)
void gemm_nt_guard(const short* __restrict__ A, const short* __restrict__ B,
                   short* __restrict__ Cout, int M, int N, int K){
  __shared__ short As[128][72];
  __shared__ short Bs[128][72];
  int tid = threadIdx.x;
  int wave = tid>>6, lane = tid&63, quad = lane>>4, l16 = lane&15;
  int m0 = blockIdx.x*128, n0 = blockIdx.y*128;
  int wm = (wave>>1)*64, wn = (wave&1)*64;
  floatx4 acc[4][4] = {};

  for (int k0 = 0; k0 < K; k0 += 64){
    __syncthreads();
    #pragma unroll
    for (int i=0;i<4;i++){
      int c = tid + 256*i;
      int r = c>>3, cc = (c&7)*8;
      *(short8v*)&As[r][cc] = *(const short8v*)&A[(size_t)(m0+r)*K + k0 + cc];
      int bn = n0 + r;
      int bcl = bn < N ? bn : 0;
      *(short8v*)&Bs[r][cc] = *(const short8v*)&B[(size_t)bcl*K + k0 + cc];
    }
    __syncthreads();
    #pragma unroll
    for (int ks=0; ks<2; ks++){
      short8v af[4], bf[4];
      #pragma unroll
      for (int i=0;i<4;i++) af[i] = *(short8v*)&As[wm + i*16 + l16][ks*32 + quad*8];
      #pragma unroll
      for (int j=0;j<4;j++) bf[j] = *(short8v*)&Bs[wn + j*16 + l16][ks*32 + quad*8];
      #pragma unroll
      for (int i=0;i<4;i++)
        #pragma unroll
        for (int j=0;j<4;j++)
          acc[i][j] = __builtin_amdgcn_mfma_f32_16x16x32_bf16(af[i], bf[j], acc[i][j], 0,0,0);
    }
  }
  #pragma unroll
  for (int i=0;i<4;i++){
    #pragma unroll
    for (int r=0;r<4;r++){
      int gm = m0 + wm + i*16 + quad*4 + r;
      #pragma unroll
      for (int j=0;j<4;j++){
        int gn = n0 + wn + j*16 + l16;
        if (gn < N) Cout[(size_t)gm*N + gn] = f2bf(acc[i][j][r]);
      }
    }
  }
}

// ---------------- RoPE on Q and K in place (bf16) ----------------
__global__ __launch_bounds__(256) void rope_k(short* __restrict__ Q, short* __restrict__ Kv,
                                              const float* __restrict__ fcos,
                                              const float* __restrict__ fsin){
  int i = blockIdx.x*256 + threadIdx.x;
  int row = i >> 10;
  int p = i & 1023;
  int s = row & (S_-1);
  int pp = p & 63;
  float c = fcos[s*64+pp], sn = fsin[s*64+pp];
  size_t a = (size_t)row*DIM_ + p*2;
  {
    int v = *(int*)(Q + a);
    float re = bf2f((short)(v & 0xffff)), im = bf2f((short)(v >> 16));
    float orr = re*c - im*sn, oi = re*sn + im*c;
    *(int*)(Q + a) = ((int)(unsigned short)f2bf(oi) << 16) | (unsigned short)f2bf(orr);
  }
  {
    int v = *(int*)(Kv + a);
    float re = bf2f((short)(v & 0xffff)), im = bf2f((short)(v >> 16));
    float orr = re*c - im*sn, oi = re*sn + im*c;
    *(int*)(Kv + a) = ((int)(unsigned short)f2bf(oi) << 16) | (unsigned short)f2bf(orr);
  }
}

// ---------------- V transpose: Vt[b*2048 + n][s] = V[b*2048 + s][n] ---------
__global__ __launch_bounds__(256) void transpose_k(const short* __restrict__ V,
                                                   short* __restrict__ Vt){
  __shared__ short t[64][72];
  int b = blockIdx.z;
  int s0 = blockIdx.x*64, n0 = blockIdx.y*64;
  int tid = threadIdx.x;
  #pragma unroll
  for (int i=0;i<2;i++){
    int c = tid + 256*i;
    int r = c>>3, cc = (c&7)*8;
    *(short8v*)&t[r][cc] = *(const short8v*)&V[((size_t)(b*2048 + s0 + r))*2048 + n0 + cc];
  }
  __syncthreads();
  #pragma unroll
  for (int i=0;i<2;i++){
    int c = tid + 256*i;
    int r = c>>3, cc = (c&7)*8;
    short8v v;
    #pragma unroll
    for (int u=0;u<8;u++) v[u] = t[cc+u][r];
    *(short8v*)&Vt[((size_t)(b*2048 + n0 + r))*2048 + s0 + cc] = v;
  }
}

// ---------------- Flash attention, pair-balanced, no online max -------------
// Block handles q-tiles qtL=pi and qtH=31-pi (BQ=64 each), shared K/V/KH tiles.
__global__ __launch_bounds__(256,2)
void flash_k(const short* __restrict__ Q, const short* __restrict__ Kk,
             const short* __restrict__ Vt, const short* __restrict__ QKH,
             short* __restrict__ O){
  int pi = blockIdx.x, h = blockIdx.y, b = blockIdx.z;
  int qtL = pi, qtH = 31 - pi;
  int tid = threadIdx.x, wave = tid>>6, lane = tid&63, quad = lane>>4, l16 = lane&15;

  __shared__ short Ks [64][128];
  __shared__ short Vts[128][64];
  __shared__ short KHs[64][32];
  __shared__ short Ps [4][16][72];

  const float CS = 1.44269504f * 0.08838834764831845f;  // log2(e)/sqrt(128)
  const float NL2E = -1.44269504f;

  short8v qfL[4], qfH[4];
  size_t qrowL = (size_t)(b*2048 + qtL*64 + wave*16 + l16);
  size_t qrowH = (size_t)(b*2048 + qtH*64 + wave*16 + l16);
  #pragma unroll
  for (int ks=0;ks<4;ks++){
    qfL[ks] = *(const short8v*)&Q[qrowL*2048 + h*128 + ks*32 + quad*8];
    qfH[ks] = *(const short8v*)&Q[qrowH*2048 + h*128 + ks*32 + quad*8];
  }
  short8v qhL = *(const short8v*)&QKH[qrowL*64 + quad*8];
  short8v qhH = *(const short8v*)&QKH[qrowH*64 + quad*8];

  floatx4 oaccL[8] = {}, oaccH[8] = {};
  float lpL[4] = {0.f,0.f,0.f,0.f}, lpH[4] = {0.f,0.f,0.f,0.f};

  auto strip = [&](const short8v* qf, short8v qh, int qt, int kt,
                   floatx4* oacc, float* lp){
    floatx4 sacc[4] = {};
    floatx4 am[4];
    #pragma unroll
    for (int j=0;j<4;j++){
      #pragma unroll
      for (int ks2=0;ks2<4;ks2++){
        short8v kf = *(short8v*)&Ks[j*16+l16][ks2*32+quad*8];
        sacc[j] = __builtin_amdgcn_mfma_f32_16x16x32_bf16(qf[ks2], kf, sacc[j], 0,0,0);
      }
      short8v khf = *(short8v*)&KHs[j*16+l16][quad*8];
      floatx4 z = {0.f,0.f,0.f,0.f};
      am[j] = __builtin_amdgcn_mfma_f32_16x16x32_bf16(qh, khf, z, 0,0,0);
    }
    if (kt < qt){
      #pragma unroll
      for (int j=0;j<4;j++){
        #pragma unroll
        for (int r=0;r<4;r++){
          float p = __builtin_amdgcn_exp2f(sacc[j][r]*CS);
          float g = __builtin_amdgcn_rcpf(1.f + __builtin_amdgcn_exp2f(am[j][r]*NL2E));
          lp[r] += p;
          Ps[wave][quad*4+r][j*16+l16] = f2bf(p*g);
        }
      }
    } else {  // diagonal tile: kt == qt
      int qin = wave*16 + quad*4;
      #pragma unroll
      for (int j=0;j<4;j++){
        int kin = j*16 + l16;
        #pragma unroll
        for (int r=0;r<4;r++){
          float p = (kin <= qin + r) ? __builtin_amdgcn_exp2f(sacc[j][r]*CS) : 0.f;
          float g = __builtin_amdgcn_rcpf(1.f + __builtin_amdgcn_exp2f(am[j][r]*NL2E));
          lp[r] += p;
          Ps[wave][quad*4+r][j*16+l16] = f2bf(p*g);
        }
      }
    }
    #pragma unroll
    for (int ks2=0; ks2<2; ks2++){
      short8v pf = *(short8v*)&Ps[wave][l16][ks2*32 + quad*8];
      #pragma unroll
      for (int dt=0; dt<8; dt++){
        short8v vf = *(short8v*)&Vts[dt*16 + l16][ks2*32 + quad*8];
        oacc[dt] = __builtin_amdgcn_mfma_f32_16x16x32_bf16(pf, vf, oacc[dt], 0,0,0);
      }
    }
  };

  for (int kt=0; kt<=qtH; kt++){
    int k0 = kt*64;
    __syncthreads();
    const short* Kt  = Kk + ((size_t)(b*2048 + k0))*2048 + h*128;
    const short* Vb2 = Vt + ((size_t)(b*2048 + h*128))*2048 + k0;
    #pragma unroll
    for (int i=0;i<4;i++){
      __builtin_amdgcn_global_load_lds(ASG(Kt + (size_t)(wave*16 + i*4 + (lane>>4))*2048 + (lane&15)*8),
                                       ASL(&Ks[wave*16 + i*4][0]), 16, 0, 0);
      __builtin_amdgcn_global_load_lds(ASG(Vb2 + (size_t)(wave*32 + i*8 + (lane>>3))*2048 + (lane&7)*8),
                                       ASL(&Vts[wave*32 + i*8][0]), 16, 0, 0);
    }
    __builtin_amdgcn_global_load_lds(ASG(QKH + (size_t)(b*2048 + k0 + wave*16 + (lane>>2))*64 + 32 + (lane&3)*8),
                                     ASL(&KHs[wave*16][0]), 16, 0, 0);
    __syncthreads();
    strip(qfH, qhH, qtH, kt, oaccH, lpH);
    if (kt <= qtL) strip(qfL, qhL, qtL, kt, oaccL, lpL);
  }

  #pragma unroll
  for (int r=0;r<4;r++){
    #pragma unroll
    for (int off=1; off<16; off<<=1){
      lpL[r] += __shfl_xor(lpL[r], off, 64);
      lpH[r] += __shfl_xor(lpH[r], off, 64);
    }
  }
  #pragma unroll
  for (int r=0;r<4;r++){
    float invL = __builtin_amdgcn_rcpf(lpL[r]);
    float invH = __builtin_amdgcn_rcpf(lpH[r]);
    size_t orL = (size_t)(b*2048 + qtL*64 + wave*16 + quad*4 + r);
    size_t orH = (size_t)(b*2048 + qtH*64 + wave*16 + quad*4 + r);
    #pragma unroll
    for (int dt=0;dt<8;dt++){
      O[orL*2048 + h*128 + dt*16 + l16] = f2bf(oaccL[dt][r]*invL);
      O[orH*2048 + h*128 + dt*16 + l16] = f2bf(oaccH[dt][r]*invH);
    }
  }
}

// ---------------- launch ----------------
extern "C" void kernel_launch(void* const* d_in, const int* in_sizes, int n_in,
                              void* d_out, int out_size, void* d_ws, size_t ws_size,
                              hipStream_t stream){
  const float* x    = (const float*)d_in[0];
  const float* fcos = (const float*)d_in[2];
  const float* fsin = (const float*)d_in[3];
  const float* wq   = (const float*)d_in[4];
  const float* wk   = (const float*)d_in[5];
  const float* wv   = (const float*)d_in[6];
  const float* wo   = (const float*)d_in[7];
  const float* waq  = (const float*)d_in[8];
  const float* wak  = (const float*)d_in[9];
  float* out = (float*)d_out;

  char* ws = (char*)d_ws;
  size_t off = 0;
  const size_t SZ_ACT = (size_t)4096*2048*2;
  const size_t SZ_W   = (size_t)2048*2048*2;
  short* xb   = (short*)(ws + off); off += SZ_ACT;
  short* wqb  = (short*)(ws + off); off += SZ_W;
  short* wkb  = (short*)(ws + off); off += SZ_W;
  short* wvb  = (short*)(ws + off); off += SZ_W;
  short* wob  = (short*)(ws + off); off += SZ_W;
  short* wab  = (short*)(ws + off); off += (size_t)64*2048*2;
  short* Qb   = (short*)(ws + off); off += SZ_ACT;
  short* Kb   = (short*)(ws + off); off += SZ_ACT;
  short* Vb   = (short*)(ws + off); off += SZ_ACT;
  short* Vtb  = (short*)(ws + off); off += SZ_ACT;
  short* xqkh = (short*)(ws + off); off += (size_t)4096*64*2;
  short* Ob   = xb;

  cvt_k<<<8192,256,0,stream>>>(x,   xb,  8388608);
  cvt_k<<<4096,256,0,stream>>>(wq,  wqb, 4194304);
  cvt_k<<<4096,256,0,stream>>>(wk,  wkb, 4194304);
  cvt_k<<<4096,256,0,stream>>>(wv,  wvb, 4194304);
  cvt_k<<<4096,256,0,stream>>>(wo,  wob, 4194304);
  cvt_k<<<64,  256,0,stream>>>(waq, wab,         65536);
  cvt_k<<<64,  256,0,stream>>>(wak, wab + 65536, 65536);

  dim3 gBig(32,16);
  gemm_nt_fast<true><<<gBig,256,0,stream>>>(xb, wqb, Qb, 4096, 2048, 2048);
  gemm_nt_fast<true><<<gBig,256,0,stream>>>(xb, wkb, Kb, 4096, 2048, 2048);
  gemm_nt_fast<true><<<gBig,256,0,stream>>>(xb, wvb, Vb, 4096, 2048, 2048);
  gemm_nt_guard<<<dim3(32,1),256,0,stream>>>(xb, wab, xqkh, 4096, 64, 2048);

  rope_k<<<16384,256,0,stream>>>(Qb, Kb, fcos, fsin);
  transpose_k<<<dim3(32,32,2),256,0,stream>>>(Vb, Vtb);

  flash_k<<<dim3(16,16,2),256,0,stream>>>(Qb, Kb, Vtb, xqkh, Ob);

  gemm_nt_fast<false><<<gBig,256,0,stream>>>(Ob, wob, out, 4096, 2048, 2048);
}

// Round 3
// 447.952 us; speedup vs baseline: 1.7626x; 1.3847x over previous
//
#include <hip/hip_runtime.h>

typedef __attribute__((ext_vector_type(8))) short short8v;
typedef __attribute__((ext_vector_type(4))) short short4v;
typedef __attribute__((ext_vector_type(4))) float floatx4;

#define S_    2048
#define DIM_  2048

#define ASG(p) ((__attribute__((address_space(1))) void*)(p))
#define ASL(p) ((__attribute__((address_space(3))) void*)(p))

__device__ __forceinline__ short f2bf(float f){
  union { float f; unsigned u; } c; c.f = f;
  unsigned u = c.u;
  unsigned r = (u + 0x7fffu + ((u >> 16) & 1u)) >> 16;
  return (short)r;
}
__device__ __forceinline__ float bf2f(short s){
  union { unsigned u; float f; } c; c.u = ((unsigned)(unsigned short)s) << 16;
  return c.f;
}

// ---------------- f32 -> bf16 convert ----------------
__global__ __launch_bounds__(256) void cvt_k(const float* __restrict__ in,
                                             short* __restrict__ out, int n){
  int i = blockIdx.x*256 + threadIdx.x;
  int idx = i*4;
  if (idx >= n) return;
  floatx4 v = *(const floatx4*)(in + idx);
  short4v o;
  o[0]=f2bf(v[0]); o[1]=f2bf(v[1]); o[2]=f2bf(v[2]); o[3]=f2bf(v[3]);
  *(short4v*)(out + idx) = o;
}

// ------------- fast NT GEMM, XOR-swizzled LDS (conflict-free column reads) --
// C[m,n] = sum_k A[m,k]*B[n,k]. 128x128 tile, BK=64, global_load_lds staging.
// LDS layout: row r, 16B-chunk stored at position (chunk ^ (r&7)).
template<bool OUT_BF16>
__global__ __launch_bounds__(256,2)
void gemm_nt_fast(const short* __restrict__ A, const short* __restrict__ B,
                  void* __restrict__ Cout, int M, int N, int K){
  __shared__ short As[128][64];
  __shared__ short Bs[128][64];
  int tid = threadIdx.x;
  int wave = tid>>6, lane = tid&63, quad = lane>>4, l16 = lane&15;
  int l7 = l16&7;
  int m0 = blockIdx.x*128, n0 = blockIdx.y*128;
  int wm = (wave>>1)*64, wn = (wave&1)*64;
  floatx4 acc[4][4] = {};

  int lr = lane>>3;                       // 0..7 (row within 8-row group)
  int sw = (lane&7) ^ lr;                 // swizzled source chunk
  const short* Abase = A + (size_t)(m0 + wave*32 + lr)*K + sw*8;
  const short* Bbase = B + (size_t)(n0 + wave*32 + lr)*K + sw*8;

  for (int k0 = 0; k0 < K; k0 += 64){
    __syncthreads();
    #pragma unroll
    for (int i=0;i<4;i++){
      __builtin_amdgcn_global_load_lds(ASG(Abase + (size_t)(i*8)*K + k0),
                                       ASL(&As[wave*32 + i*8][0]), 16, 0, 0);
      __builtin_amdgcn_global_load_lds(ASG(Bbase + (size_t)(i*8)*K + k0),
                                       ASL(&Bs[wave*32 + i*8][0]), 16, 0, 0);
    }
    __syncthreads();
    #pragma unroll
    for (int ks=0; ks<2; ks++){
      short8v af[4], bf[4];
      #pragma unroll
      for (int i=0;i<4;i++) af[i] = *(short8v*)&As[wm + i*16 + l16][((ks*4+quad)^l7)*8];
      #pragma unroll
      for (int j=0;j<4;j++) bf[j] = *(short8v*)&Bs[wn + j*16 + l16][((ks*4+quad)^l7)*8];
      #pragma unroll
      for (int i=0;i<4;i++)
        #pragma unroll
        for (int j=0;j<4;j++)
          acc[i][j] = __builtin_amdgcn_mfma_f32_16x16x32_bf16(af[i], bf[j], acc[i][j], 0,0,0);
    }
  }
  #pragma unroll
  for (int i=0;i<4;i++){
    #pragma unroll
    for (int r=0;r<4;r++){
      int gm = m0 + wm + i*16 + quad*4 + r;
      #pragma unroll
      for (int j=0;j<4;j++){
        int gn = n0 + wn + j*16 + l16;
        if (OUT_BF16) ((short*)Cout)[(size_t)gm*N + gn] = f2bf(acc[i][j][r]);
        else          ((float*)Cout)[(size_t)gm*N + gn] = acc[i][j][r];
      }
    }
  }
}

// ---------------- RoPE: Q (stride 2176, first 2048 cols) and K (stride 2048)
__global__ __launch_bounds__(256) void rope_k(short* __restrict__ Q, short* __restrict__ Kv,
                                              const float* __restrict__ fcos,
                                              const float* __restrict__ fsin){
  int i = blockIdx.x*256 + threadIdx.x;
  int row = i >> 10;
  int p = i & 1023;
  int s = row & (S_-1);
  int pp = p & 63;
  float c = fcos[s*64+pp], sn = fsin[s*64+pp];
  {
    size_t a = (size_t)row*2176 + p*2;
    int v = *(int*)(Q + a);
    float re = bf2f((short)(v & 0xffff)), im = bf2f((short)(v >> 16));
    float orr = re*c - im*sn, oi = re*sn + im*c;
    *(int*)(Q + a) = ((int)(unsigned short)f2bf(oi) << 16) | (unsigned short)f2bf(orr);
  }
  {
    size_t a = (size_t)row*2048 + p*2;
    int v = *(int*)(Kv + a);
    float re = bf2f((short)(v & 0xffff)), im = bf2f((short)(v >> 16));
    float orr = re*c - im*sn, oi = re*sn + im*c;
    *(int*)(Kv + a) = ((int)(unsigned short)f2bf(oi) << 16) | (unsigned short)f2bf(orr);
  }
}

// ---------------- V transpose: Vt[b*2048 + n][s] = V[b*2048 + s][n] ---------
__global__ __launch_bounds__(256) void transpose_k(const short* __restrict__ V,
                                                   short* __restrict__ Vt){
  __shared__ short t[64][72];
  int b = blockIdx.z;
  int s0 = blockIdx.x*64, n0 = blockIdx.y*64;
  int tid = threadIdx.x;
  #pragma unroll
  for (int i=0;i<2;i++){
    int c = tid + 256*i;
    int r = c>>3, cc = (c&7)*8;
    *(short8v*)&t[r][cc] = *(const short8v*)&V[((size_t)(b*2048 + s0 + r))*2048 + n0 + cc];
  }
  __syncthreads();
  #pragma unroll
  for (int i=0;i<2;i++){
    int c = tid + 256*i;
    int r = c>>3, cc = (c&7)*8;
    short8v v;
    #pragma unroll
    for (int u=0;u<8;u++) v[u] = t[cc+u][r];
    *(short8v*)&Vt[((size_t)(b*2048 + n0 + r))*2048 + s0 + cc] = v;
  }
}

// ---------------- Flash attention, paired q-tiles processed SEQUENTIALLY ----
// Block pi handles q-tile 31-pi then q-tile pi: 33 strips total (balanced).
// Qc: (B*S, 2176) = [Q(rope'd) | xq_h | xk_h]. K: (B*S,2048). Vt: (B*2048,S).
// Swizzled LDS: chunk' = chunk ^ (row&7) for Ks and Vts.
__global__ __launch_bounds__(256,2)
void flash_k(const short* __restrict__ Qc, const short* __restrict__ Kk,
             const short* __restrict__ Vt, short* __restrict__ O){
  int pi = blockIdx.x, h = blockIdx.y, b = blockIdx.z;
  int tid = threadIdx.x, wave = tid>>6, lane = tid&63, quad = lane>>4, l16 = lane&15;
  int l7 = l16&7;

  __shared__ short Ks [64][128];
  __shared__ short Vts[128][64];
  __shared__ short KHs[64][40];
  __shared__ short Ps [4][16][72];

  const float CS = 1.44269504f * 0.08838834764831845f;  // log2(e)/sqrt(128)
  const float NL2E = -1.44269504f;

  for (int ph = 0; ph < 2; ph++){
    int qt = ph ? pi : 31 - pi;
    size_t qrow = (size_t)(b*2048 + qt*64 + wave*16 + l16);
    short8v qf[4];
    #pragma unroll
    for (int ks=0;ks<4;ks++)
      qf[ks] = *(const short8v*)&Qc[qrow*2176 + h*128 + ks*32 + quad*8];
    short8v qh = *(const short8v*)&Qc[qrow*2176 + 2048 + quad*8];

    floatx4 oacc[8] = {};
    float lp[4] = {0.f,0.f,0.f,0.f};

    for (int kt=0; kt<=qt; kt++){
      int k0 = kt*64;
      __syncthreads();
      {
        // K tile: 64 rows x 128 shorts (16 chunks); swizzle chunk^(row&7)
        const short* Ksrc = Kk + ((size_t)(b*2048 + k0 + wave*16))*2048 + h*128;
        int r4 = lane>>4, c16 = lane&15;
        #pragma unroll
        for (int j=0;j<4;j++)
          __builtin_amdgcn_global_load_lds(
            ASG(Ksrc + (size_t)(j*4 + r4)*2048 + ((c16 ^ r4 ^ ((j&1)*4))*8)),
            ASL(&Ks[wave*16 + j*4][0]), 16, 0, 0);
        // V tile: 128 rows x 64 shorts (8 chunks)
        const short* Vsrc = Vt + ((size_t)(b*2048 + h*128 + wave*32 + (lane>>3)))*2048 + k0
                            + (((lane&7) ^ (lane>>3))*8);
        #pragma unroll
        for (int j=0;j<4;j++)
          __builtin_amdgcn_global_load_lds(
            ASG(Vsrc + (size_t)(j*8)*2048),
            ASL(&Vts[wave*32 + j*8][0]), 16, 0, 0);
        // xk_h tile: 64 rows x 32 shorts, padded LDS (regular staging)
        int r = tid>>2, c = tid&3;
        short8v kh = *(const short8v*)&Qc[(size_t)(b*2048 + k0 + r)*2176 + 2080 + c*8];
        *(short8v*)&KHs[r][c*8] = kh;
      }
      __syncthreads();

      floatx4 sacc[4] = {};
      #pragma unroll
      for (int j=0;j<4;j++)
        #pragma unroll
        for (int ks2=0;ks2<4;ks2++){
          short8v kf = *(short8v*)&Ks[j*16+l16][((ks2*4+quad)^l7)*8];
          sacc[j] = __builtin_amdgcn_mfma_f32_16x16x32_bf16(qf[ks2], kf, sacc[j], 0,0,0);
        }
      floatx4 am[4];
      #pragma unroll
      for (int j=0;j<4;j++){
        short8v khf = *(short8v*)&KHs[j*16+l16][quad*8];
        floatx4 z = {0.f,0.f,0.f,0.f};
        am[j] = __builtin_amdgcn_mfma_f32_16x16x32_bf16(qh, khf, z, 0,0,0);
      }
      bool diag = (kt == qt);
      int qin = wave*16 + quad*4;
      #pragma unroll
      for (int j=0;j<4;j++){
        int kin = j*16 + l16;
        #pragma unroll
        for (int r=0;r<4;r++){
          bool keep = !diag || (kin <= qin + r);
          float p = keep ? __builtin_amdgcn_exp2f(sacc[j][r]*CS) : 0.f;
          float g = __builtin_amdgcn_rcpf(1.f + __builtin_amdgcn_exp2f(am[j][r]*NL2E));
          lp[r] += p;
          Ps[wave][quad*4+r][j*16+l16] = f2bf(p*g);
        }
      }
      #pragma unroll
      for (int ks2=0; ks2<2; ks2++){
        short8v pf = *(short8v*)&Ps[wave][l16][ks2*32 + quad*8];
        #pragma unroll
        for (int dt=0; dt<8; dt++){
          short8v vf = *(short8v*)&Vts[dt*16 + l16][((ks2*4+quad)^l7)*8];
          oacc[dt] = __builtin_amdgcn_mfma_f32_16x16x32_bf16(pf, vf, oacc[dt], 0,0,0);
        }
      }
    }

    #pragma unroll
    for (int r=0;r<4;r++)
      #pragma unroll
      for (int off=1; off<16; off<<=1)
        lp[r] += __shfl_xor(lp[r], off, 64);
    #pragma unroll
    for (int r=0;r<4;r++){
      float inv = __builtin_amdgcn_rcpf(lp[r]);
      size_t orow = (size_t)(b*2048 + qt*64 + wave*16 + quad*4 + r);
      #pragma unroll
      for (int dt=0;dt<8;dt++)
        O[orow*2048 + h*128 + dt*16 + l16] = f2bf(oacc[dt][r]*inv);
    }
  }
}

// ---------------- launch ----------------
extern "C" void kernel_launch(void* const* d_in, const int* in_sizes, int n_in,
                              void* d_out, int out_size, void* d_ws, size_t ws_size,
                              hipStream_t stream){
  const float* x    = (const float*)d_in[0];
  const float* fcos = (const float*)d_in[2];
  const float* fsin = (const float*)d_in[3];
  const float* wq   = (const float*)d_in[4];
  const float* wk   = (const float*)d_in[5];
  const float* wv   = (const float*)d_in[6];
  const float* wo   = (const float*)d_in[7];
  const float* waq  = (const float*)d_in[8];
  const float* wak  = (const float*)d_in[9];
  float* out = (float*)d_out;

  char* ws = (char*)d_ws;
  size_t off = 0;
  const size_t SZ_ACT = (size_t)4096*2048*2;
  const size_t SZ_W   = (size_t)2048*2048*2;
  short* xb   = (short*)(ws + off); off += SZ_ACT;                  // also Ob
  short* Wcat = (short*)(ws + off); off += (size_t)2176*2048*2;     // [wq; wa_q; wa_k; pad]
  short* wkb  = (short*)(ws + off); off += SZ_W;
  short* wvb  = (short*)(ws + off); off += SZ_W;
  short* wob  = (short*)(ws + off); off += SZ_W;
  short* Qcat = (short*)(ws + off); off += (size_t)4096*2176*2;     // [Q | xq_h | xk_h]
  short* Kb   = (short*)(ws + off); off += SZ_ACT;
  short* Vb   = (short*)(ws + off); off += SZ_ACT;
  short* Vtb  = (short*)(ws + off); off += SZ_ACT;
  short* Ob   = xb;

  cvt_k<<<8192,256,0,stream>>>(x,   xb,  8388608);
  cvt_k<<<4096,256,0,stream>>>(wq,  Wcat, 4194304);
  cvt_k<<<64,  256,0,stream>>>(waq, Wcat + 4194304, 65536);   // rows 2048..2079
  cvt_k<<<64,  256,0,stream>>>(wak, Wcat + 4259840, 65536);   // rows 2080..2111
  cvt_k<<<4096,256,0,stream>>>(wk,  wkb, 4194304);
  cvt_k<<<4096,256,0,stream>>>(wv,  wvb, 4194304);
  cvt_k<<<4096,256,0,stream>>>(wo,  wob, 4194304);

  gemm_nt_fast<true><<<dim3(32,17),256,0,stream>>>(xb, Wcat, Qcat, 4096, 2176, 2048);
  gemm_nt_fast<true><<<dim3(32,16),256,0,stream>>>(xb, wkb, Kb, 4096, 2048, 2048);
  gemm_nt_fast<true><<<dim3(32,16),256,0,stream>>>(xb, wvb, Vb, 4096, 2048, 2048);

  rope_k<<<16384,256,0,stream>>>(Qcat, Kb, fcos, fsin);
  transpose_k<<<dim3(32,32,2),256,0,stream>>>(Vb, Vtb);

  flash_k<<<dim3(16,16,2),256,0,stream>>>(Qcat, Kb, Vtb, Ob);

  gemm_nt_fast<false><<<dim3(32,16),256,0,stream>>>(Ob, wob, out, 4096, 2048, 2048);
}

// Round 4
// 422.587 us; speedup vs baseline: 1.8684x; 1.0600x over previous
//
#include <hip/hip_runtime.h>

typedef __attribute__((ext_vector_type(8))) short short8v;
typedef __attribute__((ext_vector_type(4))) short short4v;
typedef __attribute__((ext_vector_type(4))) float floatx4;

#define S_    2048
#define DIM_  2048
#define NW_   6272   // fused weight rows: wq 0..2047 | waq 2048..2079 | wak 2080..2111 | wk 2112..4159 | pad 4160..4223 | wv 4224..6271

#define ASG(p) ((__attribute__((address_space(1))) void*)(p))
#define ASL(p) ((__attribute__((address_space(3))) void*)(p))

__device__ __forceinline__ short f2bf(float f){
  union { float f; unsigned u; } c; c.f = f;
  unsigned u = c.u;
  unsigned r = (u + 0x7fffu + ((u >> 16) & 1u)) >> 16;
  return (short)r;
}
__device__ __forceinline__ float bf2f(short s){
  union { unsigned u; float f; } c; c.u = ((unsigned)(unsigned short)s) << 16;
  return c.f;
}

// ---------------- f32 -> bf16 convert (x) ----------------
__global__ __launch_bounds__(256) void cvt_k(const float* __restrict__ in,
                                             short* __restrict__ out, int n){
  int i = blockIdx.x*256 + threadIdx.x;
  int idx = i*4;
  if (idx >= n) return;
  floatx4 v = *(const floatx4*)(in + idx);
  short4v o;
  o[0]=f2bf(v[0]); o[1]=f2bf(v[1]); o[2]=f2bf(v[2]); o[3]=f2bf(v[3]);
  *(short4v*)(out + idx) = o;
}

// ---------------- all weights -> bf16, one launch ----------------
__global__ __launch_bounds__(256)
void cvt_w(const float* wq, const float* waq, const float* wak,
           const float* wk, const float* wv, const float* wo,
           short* Wcat, short* wob){
  const float* src; short* dst; int n;
  switch (blockIdx.y){
    case 0: src=wq;  dst=Wcat;                 n=4194304; break;
    case 1: src=waq; dst=Wcat+(size_t)2048*2048; n=65536; break;
    case 2: src=wak; dst=Wcat+(size_t)2080*2048; n=65536; break;
    case 3: src=wk;  dst=Wcat+(size_t)2112*2048; n=4194304; break;
    case 4: src=wv;  dst=Wcat+(size_t)4224*2048; n=4194304; break;
    case 5: src=wo;  dst=wob;                  n=4194304; break;
    default: { // zero pad rows 4160..4223
      int idx = (blockIdx.x*256 + threadIdx.x)*4;
      if (idx < 131072){
        short4v z = {0,0,0,0};
        *(short4v*)(Wcat + (size_t)4160*2048 + idx) = z;
      }
      return;
    }
  }
  int idx = (blockIdx.x*256 + threadIdx.x)*4;
  if (idx >= n) return;
  floatx4 v = *(const floatx4*)(src + idx);
  short4v o;
  o[0]=f2bf(v[0]); o[1]=f2bf(v[1]); o[2]=f2bf(v[2]); o[3]=f2bf(v[3]);
  *(short4v*)(dst + idx) = o;
}

// ------------- fused QKV GEMM: C = X @ Wcat^T, N=6272, K=2048 -------------
// n-tiles 0..32 -> XQKV row-major; n-tiles 33..48 (V) -> transposed into Vt.
__global__ __launch_bounds__(256,4)
void gemm_qkv(const short* __restrict__ A, const short* __restrict__ B,
              short* __restrict__ Cout, short* __restrict__ Vt){
  __shared__ short SH[2][128][64];          // SH[0]=As, SH[1]=Bs; reused as Ts
  short (*As)[64] = SH[0];
  short (*Bs)[64] = SH[1];
  const int K = 2048, N = NW_;
  int tid = threadIdx.x;
  int wave = tid>>6, lane = tid&63, quad = lane>>4, l16 = lane&15;
  int l7 = l16&7;
  int m0 = blockIdx.x*128, n0 = blockIdx.y*128;
  int wm = (wave>>1)*64, wn = (wave&1)*64;
  floatx4 acc[4][4] = {};

  int lr = lane>>3;
  int sw = (lane&7) ^ lr;
  const short* Abase = A + (size_t)(m0 + wave*32 + lr)*K + sw*8;
  const short* Bbase = B + (size_t)(n0 + wave*32 + lr)*K + sw*8;

  for (int k0 = 0; k0 < K; k0 += 64){
    __syncthreads();
    #pragma unroll
    for (int i=0;i<4;i++){
      __builtin_amdgcn_global_load_lds(ASG(Abase + (size_t)(i*8)*K + k0),
                                       ASL(&As[wave*32 + i*8][0]), 16, 0, 0);
      __builtin_amdgcn_global_load_lds(ASG(Bbase + (size_t)(i*8)*K + k0),
                                       ASL(&Bs[wave*32 + i*8][0]), 16, 0, 0);
    }
    __syncthreads();
    #pragma unroll
    for (int ks=0; ks<2; ks++){
      short8v af[4], bf[4];
      #pragma unroll
      for (int i=0;i<4;i++) af[i] = *(short8v*)&As[wm + i*16 + l16][((ks*4+quad)^l7)*8];
      #pragma unroll
      for (int j=0;j<4;j++) bf[j] = *(short8v*)&Bs[wn + j*16 + l16][((ks*4+quad)^l7)*8];
      #pragma unroll
      for (int i=0;i<4;i++)
        #pragma unroll
        for (int j=0;j<4;j++)
          acc[i][j] = __builtin_amdgcn_mfma_f32_16x16x32_bf16(af[i], bf[j], acc[i][j], 0,0,0);
    }
  }

  if (n0 < 4224){
    // normal row-major store into XQKV
    #pragma unroll
    for (int i=0;i<4;i++)
      #pragma unroll
      for (int r=0;r<4;r++){
        int gm = m0 + wm + i*16 + quad*4 + r;
        #pragma unroll
        for (int j=0;j<4;j++){
          int gn = n0 + wn + j*16 + l16;
          Cout[(size_t)gm*N + gn] = f2bf(acc[i][j][r]);
        }
      }
  } else {
    // V tiles: transpose via LDS (reuse SH), write Vt[feat][token]
    short* T = &SH[0][0][0];                // 128 x 128 shorts
    __syncthreads();                        // all As/Bs reads done
    #pragma unroll
    for (int i=0;i<4;i++){
      int mb = wm + i*16 + quad*4;
      int mc = mb>>3, mi = mb&7;
      #pragma unroll
      for (int j=0;j<4;j++){
        int n = wn + j*16 + l16;
        short4v p;
        p[0]=f2bf(acc[i][j][0]); p[1]=f2bf(acc[i][j][1]);
        p[2]=f2bf(acc[i][j][2]); p[3]=f2bf(acc[i][j][3]);
        *(short4v*)&T[n*128 + ((mc ^ (n&7))*8) + mi] = p;
      }
    }
    __syncthreads();
    int nl = tid>>1, half = tid&1;
    #pragma unroll
    for (int c=0;c<8;c++){
      int cc = half*8 + c;
      short8v v = *(short8v*)&T[nl*128 + ((cc ^ (nl&7))*8)];
      *(short8v*)&Vt[(size_t)(n0 - 4224 + nl)*4096 + m0 + cc*8] = v;
    }
  }
}

// ------------- O GEMM (unchanged m97-style, 128x128) -------------
__global__ __launch_bounds__(256,2)
void gemm_nt_f32(const short* __restrict__ A, const short* __restrict__ B,
                 float* __restrict__ Cout, int M, int N, int K){
  __shared__ short As[128][64];
  __shared__ short Bs[128][64];
  int tid = threadIdx.x;
  int wave = tid>>6, lane = tid&63, quad = lane>>4, l16 = lane&15;
  int l7 = l16&7;
  int m0 = blockIdx.x*128, n0 = blockIdx.y*128;
  int wm = (wave>>1)*64, wn = (wave&1)*64;
  floatx4 acc[4][4] = {};

  int lr = lane>>3;
  int sw = (lane&7) ^ lr;
  const short* Abase = A + (size_t)(m0 + wave*32 + lr)*K + sw*8;
  const short* Bbase = B + (size_t)(n0 + wave*32 + lr)*K + sw*8;

  for (int k0 = 0; k0 < K; k0 += 64){
    __syncthreads();
    #pragma unroll
    for (int i=0;i<4;i++){
      __builtin_amdgcn_global_load_lds(ASG(Abase + (size_t)(i*8)*K + k0),
                                       ASL(&As[wave*32 + i*8][0]), 16, 0, 0);
      __builtin_amdgcn_global_load_lds(ASG(Bbase + (size_t)(i*8)*K + k0),
                                       ASL(&Bs[wave*32 + i*8][0]), 16, 0, 0);
    }
    __syncthreads();
    #pragma unroll
    for (int ks=0; ks<2; ks++){
      short8v af[4], bf[4];
      #pragma unroll
      for (int i=0;i<4;i++) af[i] = *(short8v*)&As[wm + i*16 + l16][((ks*4+quad)^l7)*8];
      #pragma unroll
      for (int j=0;j<4;j++) bf[j] = *(short8v*)&Bs[wn + j*16 + l16][((ks*4+quad)^l7)*8];
      #pragma unroll
      for (int i=0;i<4;i++)
        #pragma unroll
        for (int j=0;j<4;j++)
          acc[i][j] = __builtin_amdgcn_mfma_f32_16x16x32_bf16(af[i], bf[j], acc[i][j], 0,0,0);
    }
  }
  #pragma unroll
  for (int i=0;i<4;i++)
    #pragma unroll
    for (int r=0;r<4;r++){
      int gm = m0 + wm + i*16 + quad*4 + r;
      #pragma unroll
      for (int j=0;j<4;j++){
        int gn = n0 + wn + j*16 + l16;
        Cout[(size_t)gm*N + gn] = acc[i][j][r];
      }
    }
}

// ---------------- RoPE on K only (in XQKV, stride 6272, offset 2112) --------
__global__ __launch_bounds__(256) void rope_k(short* __restrict__ X,
                                              const float* __restrict__ fcos,
                                              const float* __restrict__ fsin){
  int i = blockIdx.x*256 + threadIdx.x;
  int row = i >> 10;
  int p = i & 1023;
  int s = row & (S_-1);
  int pp = p & 63;
  float c = fcos[s*64+pp], sn = fsin[s*64+pp];
  size_t a = (size_t)row*NW_ + 2112 + p*2;
  int v = *(int*)(X + a);
  float re = bf2f((short)(v & 0xffff)), im = bf2f((short)(v >> 16));
  float orr = re*c - im*sn, oi = re*sn + im*c;
  *(int*)(X + a) = ((int)(unsigned short)f2bf(oi) << 16) | (unsigned short)f2bf(orr);
}

// ---------------- gate precompute: G[b][kt][q][l16*4+j] = sigmoid(qh.kh) ----
// Causal tiles only (kt <= qt). Permuted layout matches flash's lane mapping.
__global__ __launch_bounds__(256)
void gate_k(const short* __restrict__ X, short* __restrict__ G){
  int kt = blockIdx.x, qt = blockIdx.y, b = blockIdx.z;
  if (kt > qt) return;
  int tid = threadIdx.x, wave = tid>>6, lane = tid&63, quad = lane>>4, l16 = lane&15;
  const float NL2E = -1.44269504f;

  short8v qh = *(const short8v*)&X[(size_t)(b*2048 + qt*64 + wave*16 + l16)*NW_ + 2048 + quad*8];
  floatx4 am[4];
  #pragma unroll
  for (int j=0;j<4;j++){
    short8v kh = *(const short8v*)&X[(size_t)(b*2048 + kt*64 + j*16 + l16)*NW_ + 2080 + quad*8];
    floatx4 z = {0.f,0.f,0.f,0.f};
    am[j] = __builtin_amdgcn_mfma_f32_16x16x32_bf16(qh, kh, z, 0,0,0);
  }
  short* Gd = G + (((size_t)(b*32 + kt)*2048) + qt*64 + wave*16 + quad*4)*64 + l16*4;
  #pragma unroll
  for (int r=0;r<4;r++){
    short4v sv;
    #pragma unroll
    for (int j=0;j<4;j++){
      float g = __builtin_amdgcn_rcpf(1.f + __builtin_amdgcn_exp2f(am[j][r]*NL2E));
      sv[j] = f2bf(g);
    }
    *(short4v*)(Gd + (size_t)r*64) = sv;
  }
}

// ---------------- Flash attention v2: dbuf staging, precomputed gate --------
// Qc=XQKV (stride 6272): Q cols 0..2047 (unroped; roped here), K cols 2112..4159 (roped).
// Vt: [2048 feats][4096 tokens]. G: gate in permuted layout. O: (B*S,2048) bf16.
__global__ __launch_bounds__(256,2)
void flash_k(const short* __restrict__ Qc, const short* __restrict__ Vt,
             const short* __restrict__ G, const float* __restrict__ fcos,
             const float* __restrict__ fsin, short* __restrict__ O){
  int pi = blockIdx.x, h = blockIdx.y, b = blockIdx.z;
  int tid = threadIdx.x, wave = tid>>6, lane = tid&63, quad = lane>>4, l16 = lane&15;
  int l7 = l16&7;

  __shared__ short Ks [2][64][128];
  __shared__ short Vts[2][128][64];
  __shared__ short Ps [4][16][72];

  const float CS = 1.44269504f * 0.08838834764831845f;  // log2(e)/sqrt(128)

  auto stage = [&](int kt, int buf){
    int k0 = kt*64;
    const short* Ksrc = Qc + ((size_t)(b*2048 + k0 + wave*16))*NW_ + 2112 + h*128;
    int r4 = lane>>4, c16 = lane&15;
    #pragma unroll
    for (int j=0;j<4;j++)
      __builtin_amdgcn_global_load_lds(
        ASG(Ksrc + (size_t)(j*4 + r4)*NW_ + ((c16 ^ r4 ^ ((j&1)*4))*8)),
        ASL(&Ks[buf][wave*16 + j*4][0]), 16, 0, 0);
    const short* Vsrc = Vt + ((size_t)(h*128 + wave*32 + (lane>>3)))*4096 + b*2048 + k0
                        + (((lane&7) ^ (lane>>3))*8);
    #pragma unroll
    for (int j=0;j<4;j++)
      __builtin_amdgcn_global_load_lds(
        ASG(Vsrc + (size_t)(j*8)*4096),
        ASL(&Vts[buf][wave*32 + j*8][0]), 16, 0, 0);
  };

  for (int ph = 0; ph < 2; ph++){
    int qt = ph ? pi : 31 - pi;
    size_t qrow = (size_t)(b*2048 + qt*64 + wave*16 + l16);
    int srow = qt*64 + wave*16 + l16;
    short8v qf[4];
    #pragma unroll
    for (int ks=0;ks<4;ks++)
      qf[ks] = *(const short8v*)&Qc[qrow*NW_ + h*128 + ks*32 + quad*8];
    // fused RoPE on Q fragments (pairs are lane-local)
    #pragma unroll
    for (int ks=0;ks<4;ks++)
      #pragma unroll
      for (int jj=0;jj<4;jj++){
        float re = bf2f(qf[ks][2*jj]), im = bf2f(qf[ks][2*jj+1]);
        int p = ks*16 + quad*4 + jj;
        float c = fcos[srow*64 + p], sn = fsin[srow*64 + p];
        qf[ks][2*jj]   = f2bf(re*c - im*sn);
        qf[ks][2*jj+1] = f2bf(re*sn + im*c);
      }

    floatx4 oacc[8] = {};
    float lp[4] = {0.f,0.f,0.f,0.f};

    __syncthreads();          // protect buffers from previous phase's readers
    stage(0, 0);
    for (int kt=0; kt<=qt; kt++){
      __syncthreads();        // tile kt staged; prev compute done
      if (kt < qt) stage(kt+1, (kt+1)&1);
      int bc = kt&1;

      // gate loads (coalesced 8B per lane-row, L2-hot)
      const short* gb = G + (((size_t)(b*32 + kt)*2048) + qt*64 + wave*16 + quad*4)*64 + l16*4;
      short4v g4[4];
      #pragma unroll
      for (int r=0;r<4;r++) g4[r] = *(const short4v*)(gb + (size_t)r*64);

      floatx4 sacc[4] = {};
      #pragma unroll
      for (int j=0;j<4;j++)
        #pragma unroll
        for (int ks2=0;ks2<4;ks2++){
          short8v kf = *(short8v*)&Ks[bc][j*16+l16][((ks2*4+quad)^l7)*8];
          sacc[j] = __builtin_amdgcn_mfma_f32_16x16x32_bf16(qf[ks2], kf, sacc[j], 0,0,0);
        }

      bool diag = (kt == qt);
      int qin = wave*16 + quad*4;
      #pragma unroll
      for (int j=0;j<4;j++){
        int kin = j*16 + l16;
        #pragma unroll
        for (int r=0;r<4;r++){
          bool keep = !diag || (kin <= qin + r);
          float p = keep ? __builtin_amdgcn_exp2f(sacc[j][r]*CS) : 0.f;
          lp[r] += p;
          Ps[wave][quad*4+r][j*16+l16] = f2bf(p * bf2f(g4[r][j]));
        }
      }
      #pragma unroll
      for (int ks2=0; ks2<2; ks2++){
        short8v pf = *(short8v*)&Ps[wave][l16][ks2*32 + quad*8];
        #pragma unroll
        for (int dt=0; dt<8; dt++){
          short8v vf = *(short8v*)&Vts[bc][dt*16 + l16][((ks2*4+quad)^l7)*8];
          oacc[dt] = __builtin_amdgcn_mfma_f32_16x16x32_bf16(pf, vf, oacc[dt], 0,0,0);
        }
      }
    }

    #pragma unroll
    for (int r=0;r<4;r++)
      #pragma unroll
      for (int off=1; off<16; off<<=1)
        lp[r] += __shfl_xor(lp[r], off, 64);
    #pragma unroll
    for (int r=0;r<4;r++){
      float inv = __builtin_amdgcn_rcpf(lp[r]);
      size_t orow = (size_t)(b*2048 + qt*64 + wave*16 + quad*4 + r);
      #pragma unroll
      for (int dt=0;dt<8;dt++)
        O[orow*2048 + h*128 + dt*16 + l16] = f2bf(oacc[dt][r]*inv);
    }
  }
}

// ---------------- launch ----------------
extern "C" void kernel_launch(void* const* d_in, const int* in_sizes, int n_in,
                              void* d_out, int out_size, void* d_ws, size_t ws_size,
                              hipStream_t stream){
  const float* x    = (const float*)d_in[0];
  const float* fcos = (const float*)d_in[2];
  const float* fsin = (const float*)d_in[3];
  const float* wq   = (const float*)d_in[4];
  const float* wk   = (const float*)d_in[5];
  const float* wv   = (const float*)d_in[6];
  const float* wo   = (const float*)d_in[7];
  const float* waq  = (const float*)d_in[8];
  const float* wak  = (const float*)d_in[9];
  float* out = (float*)d_out;

  char* ws = (char*)d_ws;
  size_t off = 0;
  short* xb   = (short*)(ws + off); off += (size_t)4096*2048*2;   // x bf16; later G (gate)
  short* Wcat = (short*)(ws + off); off += (size_t)NW_*2048*2;    // fused weights; later O
  short* wob  = (short*)(ws + off); off += (size_t)2048*2048*2;
  short* XQKV = (short*)(ws + off); off += (size_t)4096*NW_*2;    // [Q|qh|kh|K|pad|V(unused)]
  short* Vtb  = (short*)(ws + off); off += (size_t)2048*4096*2;   // V transposed
  short* G    = xb;    // gate, overlays xb (x dead after gemm_qkv)
  short* Ob   = Wcat;  // flash output, overlays Wcat (dead after gemm_qkv)

  cvt_k<<<8192,256,0,stream>>>(x, xb, 8388608);
  cvt_w<<<dim3(4096,7),256,0,stream>>>(wq, waq, wak, wk, wv, wo, Wcat, wob);

  gemm_qkv<<<dim3(32,49),256,0,stream>>>(xb, Wcat, XQKV, Vtb);

  rope_k<<<16384,256,0,stream>>>(XQKV, fcos, fsin);
  gate_k<<<dim3(32,32,2),256,0,stream>>>(XQKV, G);

  flash_k<<<dim3(16,16,2),256,0,stream>>>(XQKV, Vtb, G, fcos, fsin, Ob);

  gemm_nt_f32<<<dim3(32,16),256,0,stream>>>(Ob, wob, out, 4096, 2048, 2048);
}